// Round 16
// baseline (244.053 us; speedup 1.0000x reference)
//
#include <hip/hip_runtime.h>

#define THREADS 256
#define BLOCKS  2048
typedef float v2f __attribute__((ext_vector_type(2)));

// tanh(x) = 1 - 2/(exp(2x)+1), pk pair (R7 form — best measured)
__device__ __forceinline__ v2f tanh2(v2f x) {
    v2f xs = x * 2.885390081777927f;                // 2*log2(e)
    v2f e  = { __builtin_amdgcn_exp2f(xs.x),
               __builtin_amdgcn_exp2f(xs.y) };
    v2f ep = e + 1.0f;
    v2f r  = { __builtin_amdgcn_rcpf(ep.x),
               __builtin_amdgcn_rcpf(ep.y) };
    return (v2f){-2.0f, -2.0f} * r + 1.0f;
}

// y[j] = tanh(b[j] + sum_k x[k]*W[k][j]) — R7's exact form (SGPR weights)
template<int IN, int OUT>
__device__ __forceinline__ void dense(const float* x, float* y,
                                      const float* __restrict__ W,
                                      const float* __restrict__ b) {
#pragma unroll
    for (int j = 0; j < OUT; j += 2) {
        v2f acc = { b[j], b[j + 1] };
#pragma unroll
        for (int k = 0; k < IN; ++k) {
            v2f w = { W[k * OUT + j], W[k * OUT + j + 1] };
            acc += w * x[k];                        // v_pk_fma_f32
        }
        v2f t = tanh2(acc);
        y[j] = t.x; y[j + 1] = t.y;
    }
}

__global__ __launch_bounds__(THREADS) void qcnn_fused(
        const float* __restrict__ inputs,
        const float* __restrict__ W_fm, const float* __restrict__ b_fm,
        const float* __restrict__ W1,  const float* __restrict__ b1,
        const float* __restrict__ Wp1, const float* __restrict__ bp1,
        const float* __restrict__ W2,  const float* __restrict__ b2,
        const float* __restrict__ Wp2, const float* __restrict__ bp2,
        const float* __restrict__ W3,  const float* __restrict__ b3,
        const float* __restrict__ protos,
        const float* __restrict__ Wh,  const float* __restrict__ bh,
        float* __restrict__ out, int B) {
    const int tid    = blockIdx.x * THREADS + threadIdx.x;
    const int stride = gridDim.x * THREADS;

    // Persistent grid-stride loop with one-iteration-ahead input prefetch:
    // the next sample's 32B is issued before the current ~4000-cyc compute,
    // hiding HBM latency entirely after the first iteration.
    const float4* in4 = reinterpret_cast<const float4*>(inputs);
    float4 c0, c1;                       // current sample's 8 features
    if (tid < B) { c0 = in4[(size_t)tid * 2]; c1 = in4[(size_t)tid * 2 + 1]; }

    for (int i = tid; i < B; i += stride) {
        const int nxt = i + stride;
        float4 n0, n1;
        if (nxt < B) {                   // prefetch next iteration's inputs
            n0 = in4[(size_t)nxt * 2];
            n1 = in4[(size_t)nxt * 2 + 1];
        }

        float xa[16], xb[16];
        xa[0] = c0.x; xa[1] = c0.y; xa[2] = c0.z; xa[3] = c0.w;
        xa[4] = c1.x; xa[5] = c1.y; xa[6] = c1.z; xa[7] = c1.w;

        dense<8, 16>(xa, xb, W_fm, b_fm);  // feature_map
        dense<16, 16>(xb, xa, W1, b1);     // conv1
        dense<16, 12>(xa, xb, Wp1, bp1);   // pool1
        dense<12, 8>(xb, xa, W2, b2);      // conv2
        dense<8, 4>(xa, xb, Wp2, bp2);     // pool2
        dense<4, 4>(xb, xa, W3, b3);       // conv3 -> xa[0..3]

        // head x-part + RBF features vs 10 prototypes (GAMMA = 1)
        v2f ha = { bh[0], 0.0f };
        ha += (v2f){ xa[0], xa[1] } * (v2f){ Wh[0], Wh[1] };
        ha += (v2f){ xa[2], xa[3] } * (v2f){ Wh[2], Wh[3] };
        float acc = ha.x + ha.y;

#pragma unroll
        for (int j = 0; j < 10; j += 2) {
            v2f d2 = { 0.0f, 0.0f };
#pragma unroll
            for (int k = 0; k < 4; ++k) {
                v2f p = { protos[j * 4 + k], protos[(j + 1) * 4 + k] };
                v2f d = (v2f){ xa[k], xa[k] } - p;
                d2 += d * d;
            }
            v2f d2s = d2 * -1.4426950408889634f;        // -log2e
            float kf0 = __builtin_amdgcn_exp2f(d2s.x);  // exp(-d2)
            float kf1 = __builtin_amdgcn_exp2f(d2s.y);
            acc = fmaf(kf0, Wh[4 + j], acc);
            acc = fmaf(kf1, Wh[5 + j], acc);
        }
        // sigmoid
        float e = __builtin_amdgcn_exp2f(acc * -1.4426950408889634f);
        out[i] = __builtin_amdgcn_rcpf(1.0f + e);

        c0 = n0; c1 = n1;                // rotate prefetched inputs
    }
}

extern "C" void kernel_launch(void* const* d_in, const int* in_sizes, int n_in,
                              void* d_out, int out_size, void* d_ws, size_t ws_size,
                              hipStream_t stream) {
    const float* inputs = (const float*)d_in[0];
    float* out = (float*)d_out;
    const int B = in_sizes[0] / 8;
    int blocks = (B + THREADS - 1) / THREADS;
    if (blocks > BLOCKS) blocks = BLOCKS;
    qcnn_fused<<<blocks, THREADS, 0, stream>>>(
        inputs,
        (const float*)d_in[1],  (const float*)d_in[2],
        (const float*)d_in[3],  (const float*)d_in[4],
        (const float*)d_in[5],  (const float*)d_in[6],
        (const float*)d_in[7],  (const float*)d_in[8],
        (const float*)d_in[9],  (const float*)d_in[10],
        (const float*)d_in[11], (const float*)d_in[12],
        (const float*)d_in[13],
        (const float*)d_in[14], (const float*)d_in[15],
        out, B);
}